// Round 1
// baseline (767.912 us; speedup 1.0000x reference)
//
#include <hip/hip_runtime.h>

typedef __attribute__((ext_vector_type(8))) __bf16 bf16x8;
typedef __attribute__((ext_vector_type(4))) float f32x4;
typedef __attribute__((ext_vector_type(8))) unsigned short u16x8;
typedef __attribute__((ext_vector_type(4))) unsigned short u16x4;

#define N_NODES 4000
#define LD 4096
#define KDIM 4000
#define D_EMB 10

__device__ __forceinline__ unsigned short f2bf(float f) {
  union { float f; unsigned int u; } v; v.f = f;
  unsigned int r = v.u + 0x7fffu + ((v.u >> 16) & 1u);
  return (unsigned short)(r >> 16);
}
__device__ __forceinline__ float bf2f(unsigned short s) {
  union { unsigned int u; float f; } v; v.u = ((unsigned int)s) << 16;
  return v.f;
}

#define AS1 __attribute__((address_space(1)))
#define AS3 __attribute__((address_space(3)))
__device__ __forceinline__ void gll16(const void* g, void* l) {
  __builtin_amdgcn_global_load_lds((const AS1 void*)g, (AS3 void*)l, 16, 0, 0);
}

// ---------- x [B,M,C] fp32 -> Xc [bc=b*64+c][m] bf16 (row stride 4096) ----------
__global__ __launch_bounds__(256) void transpose_x_kernel(const float* __restrict__ x,
                                                          unsigned short* __restrict__ Xc) {
  __shared__ float tl[64 * 65];  // stride 65: 2-way-max bank aliasing (free)
  const int t = threadIdx.x;
  const int m0 = blockIdx.x * 64;
  const int b = blockIdx.y;
#pragma unroll
  for (int rep = 0; rep < 16; ++rep) {
    int idx = rep * 256 + t;
    int ml = idx >> 6, c = idx & 63;
    int m = m0 + ml;
    tl[ml * 65 + c] = (m < N_NODES) ? x[(b * N_NODES + m) * 64 + c] : 0.f;
  }
  __syncthreads();
  const int c_out = t >> 2, q = t & 3;
  u16x8 v0, v1;
#pragma unroll
  for (int j = 0; j < 8; ++j) v0[j] = f2bf(tl[(q * 16 + j) * 65 + c_out]);
#pragma unroll
  for (int j = 0; j < 8; ++j) v1[j] = f2bf(tl[(q * 16 + 8 + j) * 65 + c_out]);
  unsigned short* dst = Xc + (size_t)(b * 64 + c_out) * LD + m0 + q * 16;
  *(u16x8*)dst = v0;
  *(u16x8*)(dst + 8) = v1;
}

// ---------- A = softmax(relu(emb @ emb^T)) rows, bf16, cols 4000..4095 zeroed ----------
__global__ __launch_bounds__(256) void build_adj_kernel(const float* __restrict__ emb,
                                                        unsigned short* __restrict__ A) {
  __shared__ float e_lds[N_NODES];
  __shared__ float embn[16];
  __shared__ float red[16];
  const int n = blockIdx.x, t = threadIdx.x;
  if (t < D_EMB) embn[t] = emb[n * D_EMB + t];
  __syncthreads();
  float lsum = 0.f;
  for (int m = t; m < N_NODES; m += 256) {
    float dot = 0.f;
#pragma unroll
    for (int d = 0; d < D_EMB; ++d) dot += embn[d] * emb[m * D_EMB + d];
    float e = __expf(fmaxf(dot, 0.f));  // exp(relu(.)); max dot ~18 -> fp32 safe w/o max-sub
    e_lds[m] = e;
    lsum += e;
  }
#pragma unroll
  for (int off = 32; off > 0; off >>= 1) lsum += __shfl_down(lsum, off, 64);
  const int lane = t & 63, wave = t >> 6;
  if (lane == 0) red[wave] = lsum;
  __syncthreads();
  if (t == 0) red[8] = 1.f / (red[0] + red[1] + red[2] + red[3]);
  __syncthreads();
  const float inv = red[8];
  for (int m = t; m < LD; m += 256) {
    float v = (m < N_NODES) ? e_lds[m] * inv : 0.f;
    A[(size_t)n * LD + m] = f2bf(v);
  }
}

// ---------- C = A @ B^T  (A:[4096,K] row-major, B:[4096,K] row-major, both bf16, ld 4096)
// m97 structure: 128x128 tile, BK=32, 4 waves (2x2 of 64x64), 16x16x32 bf16 MFMA,
// global_load_lds width-16 staging. Optionally also writes C^T via LDS transpose.
template <bool WRITE_T>
__global__ __launch_bounds__(256) void gemm_bt_kernel(const unsigned short* __restrict__ Amat,
                                                      const unsigned short* __restrict__ Bmat,
                                                      unsigned short* __restrict__ Cn,
                                                      unsigned short* __restrict__ Ct) {
  __shared__ __align__(16) char smem[WRITE_T ? (128 * 136 * 2) : (2 * 128 * 32 * 2)];
  unsigned short* At = (unsigned short*)smem;   // [128][32]
  unsigned short* Bt = At + 128 * 32;           // [128][32]
  const int tid = threadIdx.x;
  const int wave = tid >> 6, lane = tid & 63;
  const int bm = blockIdx.y * 128, bn = blockIdx.x * 128;
  const int wm = (wave >> 1) * 64, wn = (wave & 1) * 64;

  // staging: lane L of wave w loads 16B at global row (seg*16 + L/4), k-col (L%4)*8,
  // landing at LDS seg*1024 + L*16 == [row][k] layout exactly.
  const unsigned short* gA = Amat + (size_t)(bm + wave * 32 + (lane >> 2)) * LD + (lane & 3) * 8;
  const unsigned short* gB = Bmat + (size_t)(bn + wave * 32 + (lane >> 2)) * LD + (lane & 3) * 8;
  char* lA0 = smem + wave * 2048;
  char* lA1 = lA0 + 1024;
  char* lB0 = smem + 8192 + wave * 2048;
  char* lB1 = lB0 + 1024;

  f32x4 acc[4][4] = {};
  const unsigned short* Ap = At + (wm + (lane & 15)) * 32 + (lane >> 4) * 8;
  const unsigned short* Bp = Bt + (wn + (lane & 15)) * 32 + (lane >> 4) * 8;

  for (int kt = 0; kt < KDIM / 32; ++kt) {
    gll16(gA, lA0);
    gll16(gA + 16 * LD, lA1);
    gll16(gB, lB0);
    gll16(gB + 16 * LD, lB1);
    gA += 32; gB += 32;
    __syncthreads();
    bf16x8 af[4], bfr[4];
#pragma unroll
    for (int i = 0; i < 4; ++i) {
      af[i] = *(const bf16x8*)(Ap + i * 512);   // A[m=lane&15][k=quad*8+j]
      bfr[i] = *(const bf16x8*)(Bp + i * 512);  // B^T fed as B-operand: B[n=lane&15][k]
    }
#pragma unroll
    for (int mt = 0; mt < 4; ++mt)
#pragma unroll
      for (int nt = 0; nt < 4; ++nt)
        acc[mt][nt] = __builtin_amdgcn_mfma_f32_16x16x32_bf16(af[mt], bfr[nt], acc[mt][nt], 0, 0, 0);
    __syncthreads();
  }

  // normal write: C/D layout col=lane&15, row=quad*4+reg
#pragma unroll
  for (int mt = 0; mt < 4; ++mt)
#pragma unroll
    for (int nt = 0; nt < 4; ++nt)
#pragma unroll
      for (int r = 0; r < 4; ++r) {
        int row = bm + wm + mt * 16 + (lane >> 4) * 4 + r;
        int col = bn + wn + nt * 16 + (lane & 15);
        Cn[(size_t)row * LD + col] = f2bf(acc[mt][nt][r]);
      }

  if (WRITE_T) {
    unsigned short* tr = (unsigned short*)smem;  // [128 cols][136] (stride 136 = 17*8, 16B-aligned rows)
#pragma unroll
    for (int mt = 0; mt < 4; ++mt)
#pragma unroll
      for (int nt = 0; nt < 4; ++nt)
#pragma unroll
        for (int r = 0; r < 4; ++r) {
          int row = wm + mt * 16 + (lane >> 4) * 4 + r;
          int col = wn + nt * 16 + (lane & 15);
          tr[col * 136 + row] = f2bf(acc[mt][nt][r]);
        }
    __syncthreads();
    const int cl = tid >> 1, half = tid & 1;
    const unsigned short* src = tr + cl * 136 + half * 64;
    unsigned short* dst = Ct + (size_t)(bn + cl) * LD + bm + half * 64;
#pragma unroll
    for (int j = 0; j < 8; ++j)
      *(u16x8*)(dst + j * 8) = *(const u16x8*)(src + j * 8);
  }
}

// ---------- fused per-node epilogue: W_n = emb_n . wp ; out = xg @ W_n + bias_n ----------
__global__ __launch_bounds__(256) void epilogue_kernel(const float* __restrict__ x,
                                                       const float* __restrict__ emb,
                                                       const float* __restrict__ wp,
                                                       const float* __restrict__ bp,
                                                       const unsigned short* __restrict__ Y1,
                                                       const unsigned short* __restrict__ Y2,
                                                       float* __restrict__ out) {
  __shared__ unsigned short Wl[12288];  // [ki=k*64+i][o] bf16
  __shared__ unsigned short xg[12288];  // [ki][b] bf16
  __shared__ float embn[16];
  const int n = blockIdx.x, t = threadIdx.x;
  if (t < D_EMB) embn[t] = emb[n * D_EMB + t];
  __syncthreads();
#pragma unroll 4
  for (int rep = 0; rep < 48; ++rep) {
    int kio = rep * 256 + t;
    float a = 0.f;
#pragma unroll
    for (int d = 0; d < D_EMB; ++d) a += embn[d] * wp[d * 12288 + kio];
    Wl[kio] = f2bf(a);
  }
  for (int rep = 0; rep < 6; ++rep) {
    int id = rep * 256 + t;  // 1536 tasks of 8 consecutive b
    int ki = id >> 3;
    int b0 = (id & 7) * 8;
    int k = ki >> 6, i = ki & 63;
    u16x8 v;
#pragma unroll
    for (int j = 0; j < 8; ++j) {
      int b = b0 + j;
      float val;
      if (k == 0)      val = x[(size_t)(b * N_NODES + n) * 64 + i];
      else if (k == 1) val = bf2f(Y1[(size_t)n * LD + b * 64 + i]);
      else             val = 2.f * bf2f(Y2[(size_t)n * LD + b * 64 + i]) -
                             x[(size_t)(b * N_NODES + n) * 64 + i];
      v[j] = f2bf(val);
    }
    *(u16x8*)(xg + ki * 64 + b0) = v;
  }
  __syncthreads();
  const int bb0 = (t >> 4) * 4, o0 = (t & 15) * 4;
  float bias4[4];
#pragma unroll
  for (int oo = 0; oo < 4; ++oo) {
    float a = 0.f;
#pragma unroll
    for (int d = 0; d < D_EMB; ++d) a += embn[d] * bp[d * 64 + o0 + oo];
    bias4[oo] = a;
  }
  float acc[4][4] = {};
  for (int ki = 0; ki < 192; ++ki) {  // same ki for all lanes -> LDS row reads, conflict-free
    u16x4 wv = *(const u16x4*)(Wl + ki * 64 + o0);
    u16x4 xv = *(const u16x4*)(xg + ki * 64 + bb0);
    float wf[4], xf[4];
#pragma unroll
    for (int j = 0; j < 4; ++j) { wf[j] = bf2f(wv[j]); xf[j] = bf2f(xv[j]); }
#pragma unroll
    for (int j = 0; j < 4; ++j)
#pragma unroll
      for (int oo = 0; oo < 4; ++oo) acc[j][oo] += xf[j] * wf[oo];
  }
#pragma unroll
  for (int j = 0; j < 4; ++j) {
    f32x4 r;
#pragma unroll
    for (int oo = 0; oo < 4; ++oo) r[oo] = acc[j][oo] + bias4[oo];
    *(f32x4*)(out + (size_t)((bb0 + j) * N_NODES + n) * 64 + o0) = r;
  }
}

extern "C" void kernel_launch(void* const* d_in, const int* in_sizes, int n_in,
                              void* d_out, int out_size, void* d_ws, size_t ws_size,
                              hipStream_t stream) {
  const float* x   = (const float*)d_in[0];
  const float* emb = (const float*)d_in[1];
  const float* wp  = (const float*)d_in[2];
  const float* bp  = (const float*)d_in[3];
  float* out = (float*)d_out;

  // ws layout: 5 x [4096x4096] bf16 = 160 MB
  unsigned short* Xc  = (unsigned short*)d_ws;        // x^T   [bc][m]
  unsigned short* Am  = Xc  + (size_t)LD * LD;        // A     [n][m]
  unsigned short* Y1  = Am  + (size_t)LD * LD;        // A x   [n][bc]
  unsigned short* Y1t = Y1  + (size_t)LD * LD;        // (A x)^T [bc][n]
  unsigned short* Y2  = Y1t + (size_t)LD * LD;        // A^2 x [n][bc]

  transpose_x_kernel<<<dim3(63, 64), 256, 0, stream>>>(x, Xc);
  build_adj_kernel<<<N_NODES, 256, 0, stream>>>(emb, Am);
  gemm_bt_kernel<true ><<<dim3(32, 32), 256, 0, stream>>>(Am, Xc, Y1, Y1t);
  gemm_bt_kernel<false><<<dim3(32, 32), 256, 0, stream>>>(Am, Y1t, Y2, nullptr);
  epilogue_kernel<<<N_NODES, 256, 0, stream>>>(x, emb, wp, bp, Y1, Y2, out);
}

// Round 2
// 611.287 us; speedup vs baseline: 1.2562x; 1.2562x over previous
//
#include <hip/hip_runtime.h>

typedef __attribute__((ext_vector_type(8))) __bf16 bf16x8;
typedef __attribute__((ext_vector_type(4))) float f32x4;
typedef __attribute__((ext_vector_type(16))) float f32x16;
typedef __attribute__((ext_vector_type(8))) unsigned short u16x8;

#define N_NODES 4000
#define LD 4096
#define KDIM 4000
#define D_EMB 10

__device__ __forceinline__ unsigned short f2bf(float f) {
  union { float f; unsigned int u; } v; v.f = f;
  unsigned int r = v.u + 0x7fffu + ((v.u >> 16) & 1u);
  return (unsigned short)(r >> 16);
}
__device__ __forceinline__ float bf2f(unsigned short s) {
  union { unsigned int u; float f; } v; v.u = ((unsigned int)s) << 16;
  return v.f;
}

#define AS1 __attribute__((address_space(1)))
#define AS3 __attribute__((address_space(3)))
__device__ __forceinline__ void gll16(const void* g, void* l) {
  __builtin_amdgcn_global_load_lds((const AS1 void*)g, (AS3 void*)l, 16, 0, 0);
}

// ---------- x [B,M,C] fp32 -> Xc [bc=b*64+c][m] bf16 (row stride 4096) ----------
__global__ __launch_bounds__(256) void transpose_x_kernel(const float* __restrict__ x,
                                                          unsigned short* __restrict__ Xc) {
  __shared__ float tl[64 * 65];
  const int t = threadIdx.x;
  const int m0 = blockIdx.x * 64;
  const int b = blockIdx.y;
#pragma unroll
  for (int rep = 0; rep < 16; ++rep) {
    int idx = rep * 256 + t;
    int ml = idx >> 6, c = idx & 63;
    int m = m0 + ml;
    tl[ml * 65 + c] = (m < N_NODES) ? x[(b * N_NODES + m) * 64 + c] : 0.f;
  }
  __syncthreads();
  const int c_out = t >> 2, q = t & 3;
  u16x8 v0, v1;
#pragma unroll
  for (int j = 0; j < 8; ++j) v0[j] = f2bf(tl[(q * 16 + j) * 65 + c_out]);
#pragma unroll
  for (int j = 0; j < 8; ++j) v1[j] = f2bf(tl[(q * 16 + 8 + j) * 65 + c_out]);
  unsigned short* dst = Xc + (size_t)(b * 64 + c_out) * LD + m0 + q * 16;
  *(u16x8*)dst = v0;
  *(u16x8*)(dst + 8) = v1;
}

// ---------- A = softmax(relu(emb @ emb^T)) rows, bf16, cols 4000..4095 zeroed ----------
__global__ __launch_bounds__(256) void build_adj_kernel(const float* __restrict__ emb,
                                                        unsigned short* __restrict__ A) {
  __shared__ float e_lds[N_NODES];
  __shared__ float embn[16];
  __shared__ float red[16];
  const int n = blockIdx.x, t = threadIdx.x;
  if (t < D_EMB) embn[t] = emb[n * D_EMB + t];
  __syncthreads();
  float lsum = 0.f;
  for (int m = t; m < N_NODES; m += 256) {
    float dot = 0.f;
#pragma unroll
    for (int d = 0; d < D_EMB; ++d) dot += embn[d] * emb[m * D_EMB + d];
    float e = __expf(fmaxf(dot, 0.f));
    e_lds[m] = e;
    lsum += e;
  }
#pragma unroll
  for (int off = 32; off > 0; off >>= 1) lsum += __shfl_down(lsum, off, 64);
  const int lane = t & 63, wave = t >> 6;
  if (lane == 0) red[wave] = lsum;
  __syncthreads();
  if (t == 0) red[8] = 1.f / (red[0] + red[1] + red[2] + red[3]);
  __syncthreads();
  const float inv = red[8];
  for (int m = t; m < LD; m += 256) {
    float v = (m < N_NODES) ? e_lds[m] * inv : 0.f;
    A[(size_t)n * LD + m] = f2bf(v);
  }
}

// ---------- wp fp32 -> bf16 (into dead Xc region) ----------
__global__ __launch_bounds__(256) void wp_cvt_kernel(const float* __restrict__ wp,
                                                     unsigned short* __restrict__ wpb) {
  int i = blockIdx.x * 256 + threadIdx.x;  // 122880 elems
  if (i < D_EMB * 12288) wpb[i] = f2bf(wp[i]);
}

// ---------- C = A @ B^T, 128x128 tile, BK=32, 32x32x16 MFMA, 4 blocks/CU target ----------
template <bool WRITE_T>
__global__ __launch_bounds__(256, 4) void gemm_bt_kernel(const unsigned short* __restrict__ Amat,
                                                         const unsigned short* __restrict__ Bmat,
                                                         unsigned short* __restrict__ Cn,
                                                         unsigned short* __restrict__ Ct) {
  __shared__ __align__(16) char smem[WRITE_T ? (128 * 136 * 2) : (2 * 128 * 32 * 2)];
  unsigned short* At = (unsigned short*)smem;   // [128][32]
  unsigned short* Bt = At + 128 * 32;           // [128][32]
  const int tid = threadIdx.x;
  const int wave = tid >> 6, lane = tid & 63;
  const int bm = blockIdx.y * 128, bn = blockIdx.x * 128;
  const int wm = (wave >> 1) * 64, wn = (wave & 1) * 64;

  const unsigned short* gA = Amat + (size_t)(bm + wave * 32 + (lane >> 2)) * LD + (lane & 3) * 8;
  const unsigned short* gB = Bmat + (size_t)(bn + wave * 32 + (lane >> 2)) * LD + (lane & 3) * 8;
  char* lA0 = smem + wave * 2048;
  char* lA1 = lA0 + 1024;
  char* lB0 = smem + 8192 + wave * 2048;
  char* lB1 = lB0 + 1024;

  f32x16 acc[2][2] = {};  // [mt][nt], 32x32 each
  // A-frag: A[m=lane&31][k=(lane>>5)*8+j]; rows at wm + mt*32
  const unsigned short* Ap = At + (wm + (lane & 31)) * 32 + (lane >> 5) * 8;
  const unsigned short* Bp = Bt + (wn + (lane & 31)) * 32 + (lane >> 5) * 8;

  for (int kt = 0; kt < KDIM / 32; ++kt) {
    gll16(gA, lA0);
    gll16(gA + 16 * LD, lA1);
    gll16(gB, lB0);
    gll16(gB + 16 * LD, lB1);
    gA += 32; gB += 32;
    __syncthreads();
#pragma unroll
    for (int h = 0; h < 2; ++h) {  // two K=16 halves of BK=32
      bf16x8 a0 = *(const bf16x8*)(Ap + h * 16);
      bf16x8 a1 = *(const bf16x8*)(Ap + 1024 + h * 16);
      bf16x8 b0 = *(const bf16x8*)(Bp + h * 16);
      bf16x8 b1 = *(const bf16x8*)(Bp + 1024 + h * 16);
      acc[0][0] = __builtin_amdgcn_mfma_f32_32x32x16_bf16(a0, b0, acc[0][0], 0, 0, 0);
      acc[0][1] = __builtin_amdgcn_mfma_f32_32x32x16_bf16(a0, b1, acc[0][1], 0, 0, 0);
      acc[1][0] = __builtin_amdgcn_mfma_f32_32x32x16_bf16(a1, b0, acc[1][0], 0, 0, 0);
      acc[1][1] = __builtin_amdgcn_mfma_f32_32x32x16_bf16(a1, b1, acc[1][1], 0, 0, 0);
    }
    __syncthreads();
  }

  // C/D layout (32x32): col = lane&31, row = (reg&3) + 8*(reg>>2) + 4*(lane>>5)
#pragma unroll
  for (int mt = 0; mt < 2; ++mt)
#pragma unroll
    for (int nt = 0; nt < 2; ++nt)
#pragma unroll
      for (int r = 0; r < 16; ++r) {
        int row = bm + wm + mt * 32 + (r & 3) + 8 * (r >> 2) + 4 * (lane >> 5);
        int col = bn + wn + nt * 32 + (lane & 31);
        Cn[(size_t)row * LD + col] = f2bf(acc[mt][nt][r]);
      }

  if (WRITE_T) {
    unsigned short* tr = (unsigned short*)smem;  // [128 cols][136]
    __syncthreads();
#pragma unroll
    for (int mt = 0; mt < 2; ++mt)
#pragma unroll
      for (int nt = 0; nt < 2; ++nt)
#pragma unroll
        for (int r = 0; r < 16; ++r) {
          int row = wm + mt * 32 + (r & 3) + 8 * (r >> 2) + 4 * (lane >> 5);
          int col = wn + nt * 32 + (lane & 31);
          tr[col * 136 + row] = f2bf(acc[mt][nt][r]);
        }
    __syncthreads();
    const int cl = tid >> 1, half = tid & 1;
    const unsigned short* src = tr + cl * 136 + half * 64;
    unsigned short* dst = Ct + (size_t)(bn + cl) * LD + bm + half * 64;
#pragma unroll
    for (int j = 0; j < 8; ++j)
      *(u16x8*)(dst + j * 8) = *(const u16x8*)(src + j * 8);
  }
}

// ---------- fused per-node epilogue via MFMA ----------
// out[b, n, o] = sum_ki xg[b][ki] * W[ki][o] + bias[o],  per-node W = emb_n . wp
#define EST 200  // LDS row stride (elements): 400 B, 16-B aligned
__global__ __launch_bounds__(256) void epilogue_kernel(const float* __restrict__ x,
                                                       const float* __restrict__ emb,
                                                       const unsigned short* __restrict__ wpb,
                                                       const float* __restrict__ bp,
                                                       const unsigned short* __restrict__ Y1,
                                                       const unsigned short* __restrict__ Y2,
                                                       float* __restrict__ out) {
  __shared__ unsigned short Wt[64 * EST];  // [o][ki]  (B-operand: need W^T rows)
  __shared__ unsigned short xg[64 * EST];  // [b][ki]
  __shared__ float embn[16];
  const int n = blockIdx.x, t = threadIdx.x;
  if (t < D_EMB) embn[t] = emb[n * D_EMB + t];
  __syncthreads();
  // W_n[ki][o] = sum_d embn[d] * wp[d][ki][o]; store transposed Wt[o][ki]
#pragma unroll 4
  for (int rep = 0; rep < 48; ++rep) {
    int kio = rep * 256 + t;
    int ki = kio >> 6, o = kio & 63;
    float a = 0.f;
#pragma unroll
    for (int d = 0; d < D_EMB; ++d) a += embn[d] * bf2f(wpb[d * 12288 + kio]);
    Wt[o * EST + ki] = f2bf(a);
  }
  // xg[b][ki]: ki 0..63 = x, 64..127 = Y1, 128..191 = 2*Y2 - x  (coalesced per-wave reads)
#pragma unroll
  for (int rep = 0; rep < 4; ++rep) {
    int idx = rep * 256 + t;
    int b = idx >> 6, c = idx & 63;
#pragma unroll
    for (int bb = 0; bb < 16; ++bb)  // 4 b per 256-thread pass, 16 passes folded
      ;
    // (unrolled below instead)
  }
  for (int idx = t; idx < 4096; idx += 256) {
    int b = idx >> 6, c = idx & 63;
    xg[b * EST + c] = f2bf(x[(size_t)(b * N_NODES + n) * 64 + c]);
  }
  for (int idx = t; idx < 4096; idx += 256) {
    int b = idx >> 6, c = idx & 63;
    xg[b * EST + 64 + c] = Y1[(size_t)n * LD + b * 64 + c];
  }
  for (int idx = t; idx < 4096; idx += 256) {
    int b = idx >> 6, c = idx & 63;
    float v = 2.f * bf2f(Y2[(size_t)n * LD + b * 64 + c]) - bf2f(xg[b * EST + c]);
    xg[b * EST + 128 + c] = f2bf(v);
  }
  __syncthreads();

  // per-node matmul [64 b x 192 ki] @ [192 ki x 64 o] via 16x16x32 MFMA
  const int wave = t >> 6, lane = t & 63, quad = lane >> 4;
  const unsigned short* Apx = xg + (wave * 16 + (lane & 15)) * EST + quad * 8;
  f32x4 acc[4] = {};
#pragma unroll
  for (int step = 0; step < 6; ++step) {
    int koff = step * 32;
    bf16x8 a = *(const bf16x8*)(Apx + koff);
#pragma unroll
    for (int nt = 0; nt < 4; ++nt) {
      bf16x8 bfr = *(const bf16x8*)(Wt + (nt * 16 + (lane & 15)) * EST + quad * 8 + koff);
      acc[nt] = __builtin_amdgcn_mfma_f32_16x16x32_bf16(a, bfr, acc[nt], 0, 0, 0);
    }
  }
  float bias[4];
#pragma unroll
  for (int nt = 0; nt < 4; ++nt) {
    float a = 0.f;
#pragma unroll
    for (int d = 0; d < D_EMB; ++d) a += embn[d] * bp[d * 64 + nt * 16 + (lane & 15)];
    bias[nt] = a;
  }
#pragma unroll
  for (int nt = 0; nt < 4; ++nt)
#pragma unroll
    for (int r = 0; r < 4; ++r) {
      int b_row = wave * 16 + quad * 4 + r;
      out[(size_t)(b_row * N_NODES + n) * 64 + nt * 16 + (lane & 15)] = acc[nt][r] + bias[nt];
    }
}

extern "C" void kernel_launch(void* const* d_in, const int* in_sizes, int n_in,
                              void* d_out, int out_size, void* d_ws, size_t ws_size,
                              hipStream_t stream) {
  const float* x   = (const float*)d_in[0];
  const float* emb = (const float*)d_in[1];
  const float* wp  = (const float*)d_in[2];
  const float* bp  = (const float*)d_in[3];
  float* out = (float*)d_out;

  // ws layout: 5 x [4096x4096] bf16 = 160 MB
  unsigned short* Xc  = (unsigned short*)d_ws;        // x^T [bc][m]; reused for wp_bf16 after GEMM1
  unsigned short* Am  = Xc  + (size_t)LD * LD;        // A     [n][m]
  unsigned short* Y1  = Am  + (size_t)LD * LD;        // A x   [n][bc]
  unsigned short* Y1t = Y1  + (size_t)LD * LD;        // (A x)^T [bc][n]
  unsigned short* Y2  = Y1t + (size_t)LD * LD;        // A^2 x [n][bc]
  unsigned short* wpb = Xc;                           // alias: Xc dead after GEMM1

  transpose_x_kernel<<<dim3(63, 64), 256, 0, stream>>>(x, Xc);
  build_adj_kernel<<<N_NODES, 256, 0, stream>>>(emb, Am);
  gemm_bt_kernel<true ><<<dim3(32, 32), 256, 0, stream>>>(Am, Xc, Y1, Y1t);
  wp_cvt_kernel<<<480, 256, 0, stream>>>(wp, wpb);
  gemm_bt_kernel<false><<<dim3(32, 32), 256, 0, stream>>>(Am, Y1t, Y2, nullptr);
  epilogue_kernel<<<N_NODES, 256, 0, stream>>>(x, emb, wpb, bp, Y1, Y2, out);
}

// Round 3
// 595.988 us; speedup vs baseline: 1.2885x; 1.0257x over previous
//
#include <hip/hip_runtime.h>

typedef __attribute__((ext_vector_type(8))) __bf16 bf16x8;
typedef __attribute__((ext_vector_type(4))) float f32x4;
typedef __attribute__((ext_vector_type(16))) float f32x16;
typedef __attribute__((ext_vector_type(8))) unsigned short u16x8;

#define N_NODES 4000
#define LD 4096
#define KDIM 4000
#define D_EMB 10

__device__ __forceinline__ unsigned short f2bf(float f) {
  union { float f; unsigned int u; } v; v.f = f;
  unsigned int r = v.u + 0x7fffu + ((v.u >> 16) & 1u);
  return (unsigned short)(r >> 16);
}
__device__ __forceinline__ float bf2f(unsigned short s) {
  union { unsigned int u; float f; } v; v.u = ((unsigned int)s) << 16;
  return v.f;
}

#define AS1 __attribute__((address_space(1)))
#define AS3 __attribute__((address_space(3)))
__device__ __forceinline__ void gll16(const void* g, void* l) {
  __builtin_amdgcn_global_load_lds((const AS1 void*)g, (AS3 void*)l, 16, 0, 0);
}

// ---------- x [B,M,C] fp32 -> Xc [bc=b*64+c][m] bf16 (row stride 4096) ----------
__global__ __launch_bounds__(256) void transpose_x_kernel(const float* __restrict__ x,
                                                          unsigned short* __restrict__ Xc) {
  __shared__ float tl[64 * 65];
  const int t = threadIdx.x;
  const int m0 = blockIdx.x * 64;
  const int b = blockIdx.y;
#pragma unroll
  for (int rep = 0; rep < 16; ++rep) {
    int idx = rep * 256 + t;
    int ml = idx >> 6, c = idx & 63;
    int m = m0 + ml;
    tl[ml * 65 + c] = (m < N_NODES) ? x[(b * N_NODES + m) * 64 + c] : 0.f;
  }
  __syncthreads();
  const int c_out = t >> 2, q = t & 3;
  u16x8 v0, v1;
#pragma unroll
  for (int j = 0; j < 8; ++j) v0[j] = f2bf(tl[(q * 16 + j) * 65 + c_out]);
#pragma unroll
  for (int j = 0; j < 8; ++j) v1[j] = f2bf(tl[(q * 16 + 8 + j) * 65 + c_out]);
  unsigned short* dst = Xc + (size_t)(b * 64 + c_out) * LD + m0 + q * 16;
  *(u16x8*)dst = v0;
  *(u16x8*)(dst + 8) = v1;
}

// ---------- A = softmax(relu(emb @ emb^T)) rows, bf16, cols 4000..4095 zeroed ----------
__global__ __launch_bounds__(256) void build_adj_kernel(const float* __restrict__ emb,
                                                        unsigned short* __restrict__ A) {
  __shared__ float e_lds[N_NODES];
  __shared__ float embn[16];
  __shared__ float red[16];
  const int n = blockIdx.x, t = threadIdx.x;
  if (t < D_EMB) embn[t] = emb[n * D_EMB + t];
  __syncthreads();
  float lsum = 0.f;
  for (int m = t; m < N_NODES; m += 256) {
    float dot = 0.f;
#pragma unroll
    for (int d = 0; d < D_EMB; ++d) dot += embn[d] * emb[m * D_EMB + d];
    float e = __expf(fmaxf(dot, 0.f));
    e_lds[m] = e;
    lsum += e;
  }
#pragma unroll
  for (int off = 32; off > 0; off >>= 1) lsum += __shfl_down(lsum, off, 64);
  const int lane = t & 63, wave = t >> 6;
  if (lane == 0) red[wave] = lsum;
  __syncthreads();
  if (t == 0) red[8] = 1.f / (red[0] + red[1] + red[2] + red[3]);
  __syncthreads();
  const float inv = red[8];
  for (int m = t; m < LD; m += 256) {
    float v = (m < N_NODES) ? e_lds[m] * inv : 0.f;
    A[(size_t)n * LD + m] = f2bf(v);
  }
}

// ---------- wp fp32 -> bf16 (into dead Xc region) ----------
__global__ __launch_bounds__(256) void wp_cvt_kernel(const float* __restrict__ wp,
                                                     unsigned short* __restrict__ wpb) {
  int i = blockIdx.x * 256 + threadIdx.x;  // 122880 elems
  if (i < D_EMB * 12288) wpb[i] = f2bf(wp[i]);
}

// ---------- C = A @ B^T, 128x128 tile, BK=32, 32x32x16 MFMA, XOR-swizzled LDS ----------
// LDS tile [128 rows][4 chunks of 8 elem]; chunk c of row r lives at position c ^ (r&3).
// Staging: gll16 lane L lands at LDS slot [row=L>>2][pos=L&3], so lane L loads GLOBAL
// chunk (L&3)^((L>>2)&3) — swizzle is free. Fragment-read start banks spread to
// {0,4,...,28}, 8 lanes per 4-bank group = minimum phases for wave64 b128.
template <bool WRITE_T>
__global__ __launch_bounds__(256, 4) void gemm_bt_kernel(const unsigned short* __restrict__ Amat,
                                                         const unsigned short* __restrict__ Bmat,
                                                         unsigned short* __restrict__ Cn,
                                                         unsigned short* __restrict__ Ct) {
  __shared__ __align__(16) char smem[WRITE_T ? (128 * 136 * 2) : (2 * 128 * 32 * 2)];
  unsigned short* At = (unsigned short*)smem;   // [128][32] swizzled
  unsigned short* Bt = At + 128 * 32;           // [128][32] swizzled
  const int tid = threadIdx.x;
  const int wave = tid >> 6, lane = tid & 63;
  const int bm = blockIdx.y * 128, bn = blockIdx.x * 128;
  const int wm = (wave >> 1) * 64, wn = (wave & 1) * 64;

  const int swz = ((lane & 3) ^ ((lane >> 2) & 3)) * 8;  // staging source k-chunk offset
  const unsigned short* gA = Amat + (size_t)(bm + wave * 32 + (lane >> 2)) * LD + swz;
  const unsigned short* gB = Bmat + (size_t)(bn + wave * 32 + (lane >> 2)) * LD + swz;
  char* lA0 = smem + wave * 2048;
  char* lA1 = lA0 + 1024;
  char* lB0 = smem + 8192 + wave * 2048;
  char* lB1 = lB0 + 1024;

  f32x16 acc[2][2] = {};  // [mt][nt], 32x32 each
  // fragment read pointers (lane-constant, swizzled): chunk(h) = (lane>>5) | (h<<1)
  const int r = lane & 31, q = lane >> 5, rx = lane & 3;
  const unsigned short* Ap0 = At + (wm + r) * 32 + ((q ^ rx) * 8);
  const unsigned short* Ap1 = At + (wm + r) * 32 + (((q | 2) ^ rx) * 8);
  const unsigned short* Bp0 = Bt + (wn + r) * 32 + ((q ^ rx) * 8);
  const unsigned short* Bp1 = Bt + (wn + r) * 32 + (((q | 2) ^ rx) * 8);

  for (int kt = 0; kt < KDIM / 32; ++kt) {
    gll16(gA, lA0);
    gll16(gA + 16 * LD, lA1);
    gll16(gB, lB0);
    gll16(gB + 16 * LD, lB1);
    gA += 32; gB += 32;
    __syncthreads();
    {
      bf16x8 a0 = *(const bf16x8*)(Ap0);
      bf16x8 a1 = *(const bf16x8*)(Ap0 + 1024);
      bf16x8 b0 = *(const bf16x8*)(Bp0);
      bf16x8 b1 = *(const bf16x8*)(Bp0 + 1024);
      acc[0][0] = __builtin_amdgcn_mfma_f32_32x32x16_bf16(a0, b0, acc[0][0], 0, 0, 0);
      acc[0][1] = __builtin_amdgcn_mfma_f32_32x32x16_bf16(a0, b1, acc[0][1], 0, 0, 0);
      acc[1][0] = __builtin_amdgcn_mfma_f32_32x32x16_bf16(a1, b0, acc[1][0], 0, 0, 0);
      acc[1][1] = __builtin_amdgcn_mfma_f32_32x32x16_bf16(a1, b1, acc[1][1], 0, 0, 0);
    }
    {
      bf16x8 a0 = *(const bf16x8*)(Ap1);
      bf16x8 a1 = *(const bf16x8*)(Ap1 + 1024);
      bf16x8 b0 = *(const bf16x8*)(Bp1);
      bf16x8 b1 = *(const bf16x8*)(Bp1 + 1024);
      acc[0][0] = __builtin_amdgcn_mfma_f32_32x32x16_bf16(a0, b0, acc[0][0], 0, 0, 0);
      acc[0][1] = __builtin_amdgcn_mfma_f32_32x32x16_bf16(a0, b1, acc[0][1], 0, 0, 0);
      acc[1][0] = __builtin_amdgcn_mfma_f32_32x32x16_bf16(a1, b0, acc[1][0], 0, 0, 0);
      acc[1][1] = __builtin_amdgcn_mfma_f32_32x32x16_bf16(a1, b1, acc[1][1], 0, 0, 0);
    }
    __syncthreads();
  }

  // C/D layout (32x32): col = lane&31, row = (reg&3) + 8*(reg>>2) + 4*(lane>>5)
#pragma unroll
  for (int mt = 0; mt < 2; ++mt)
#pragma unroll
    for (int nt = 0; nt < 2; ++nt)
#pragma unroll
      for (int rr = 0; rr < 16; ++rr) {
        int row = bm + wm + mt * 32 + (rr & 3) + 8 * (rr >> 2) + 4 * (lane >> 5);
        int col = bn + wn + nt * 32 + (lane & 31);
        Cn[(size_t)row * LD + col] = f2bf(acc[mt][nt][rr]);
      }

  if (WRITE_T) {
    unsigned short* tr = (unsigned short*)smem;  // [128 cols][136]
    __syncthreads();
#pragma unroll
    for (int mt = 0; mt < 2; ++mt)
#pragma unroll
      for (int nt = 0; nt < 2; ++nt)
#pragma unroll
        for (int rr = 0; rr < 16; ++rr) {
          int row = wm + mt * 32 + (rr & 3) + 8 * (rr >> 2) + 4 * (lane >> 5);
          int col = wn + nt * 32 + (lane & 31);
          tr[col * 136 + row] = f2bf(acc[mt][nt][rr]);
        }
    __syncthreads();
    const int cl = tid >> 1, half = tid & 1;
    const unsigned short* src = tr + cl * 136 + half * 64;
    unsigned short* dst = Ct + (size_t)(bn + cl) * LD + bm + half * 64;
#pragma unroll
    for (int j = 0; j < 8; ++j)
      *(u16x8*)(dst + j * 8) = *(const u16x8*)(src + j * 8);
  }
}

// ---------- fused per-node epilogue via MFMA ----------
// out[b, n, o] = sum_ki xg[b][ki] * W[ki][o] + bias[o],  per-node W = emb_n . wp
#define EST 200  // LDS row stride (elements): 400 B, 16-B aligned
__global__ __launch_bounds__(256) void epilogue_kernel(const float* __restrict__ x,
                                                       const float* __restrict__ emb,
                                                       const unsigned short* __restrict__ wpb,
                                                       const float* __restrict__ bp,
                                                       const unsigned short* __restrict__ Y1,
                                                       const unsigned short* __restrict__ Y2,
                                                       float* __restrict__ out) {
  __shared__ unsigned short Wt[64 * EST];  // [o][ki]
  __shared__ unsigned short xg[64 * EST];  // [b][ki]
  __shared__ float embn[16];
  const int n = blockIdx.x, t = threadIdx.x;
  if (t < D_EMB) embn[t] = emb[n * D_EMB + t];
  __syncthreads();
#pragma unroll 4
  for (int rep = 0; rep < 48; ++rep) {
    int kio = rep * 256 + t;
    int ki = kio >> 6, o = kio & 63;
    float a = 0.f;
#pragma unroll
    for (int d = 0; d < D_EMB; ++d) a += embn[d] * bf2f(wpb[d * 12288 + kio]);
    Wt[o * EST + ki] = f2bf(a);
  }
  for (int idx = t; idx < 4096; idx += 256) {
    int b = idx >> 6, c = idx & 63;
    xg[b * EST + c] = f2bf(x[(size_t)(b * N_NODES + n) * 64 + c]);
  }
  for (int idx = t; idx < 4096; idx += 256) {
    int b = idx >> 6, c = idx & 63;
    xg[b * EST + 64 + c] = Y1[(size_t)n * LD + b * 64 + c];
  }
  for (int idx = t; idx < 4096; idx += 256) {
    int b = idx >> 6, c = idx & 63;
    float v = 2.f * bf2f(Y2[(size_t)n * LD + b * 64 + c]) - bf2f(xg[b * EST + c]);
    xg[b * EST + 128 + c] = f2bf(v);
  }
  __syncthreads();

  const int wave = t >> 6, lane = t & 63, quad = lane >> 4;
  const unsigned short* Apx = xg + (wave * 16 + (lane & 15)) * EST + quad * 8;
  f32x4 acc[4] = {};
#pragma unroll
  for (int step = 0; step < 6; ++step) {
    int koff = step * 32;
    bf16x8 a = *(const bf16x8*)(Apx + koff);
#pragma unroll
    for (int nt = 0; nt < 4; ++nt) {
      bf16x8 bfr = *(const bf16x8*)(Wt + (nt * 16 + (lane & 15)) * EST + quad * 8 + koff);
      acc[nt] = __builtin_amdgcn_mfma_f32_16x16x32_bf16(a, bfr, acc[nt], 0, 0, 0);
    }
  }
  float bias[4];
#pragma unroll
  for (int nt = 0; nt < 4; ++nt) {
    float a = 0.f;
#pragma unroll
    for (int d = 0; d < D_EMB; ++d) a += embn[d] * bp[d * 64 + nt * 16 + (lane & 15)];
    bias[nt] = a;
  }
#pragma unroll
  for (int nt = 0; nt < 4; ++nt)
#pragma unroll
    for (int rr = 0; rr < 4; ++rr) {
      int b_row = wave * 16 + quad * 4 + rr;
      out[(size_t)(b_row * N_NODES + n) * 64 + nt * 16 + (lane & 15)] = acc[nt][rr] + bias[nt];
    }
}

extern "C" void kernel_launch(void* const* d_in, const int* in_sizes, int n_in,
                              void* d_out, int out_size, void* d_ws, size_t ws_size,
                              hipStream_t stream) {
  const float* x   = (const float*)d_in[0];
  const float* emb = (const float*)d_in[1];
  const float* wp  = (const float*)d_in[2];
  const float* bp  = (const float*)d_in[3];
  float* out = (float*)d_out;

  unsigned short* Xc  = (unsigned short*)d_ws;        // x^T [bc][m]; reused for wp_bf16 after GEMM1
  unsigned short* Am  = Xc  + (size_t)LD * LD;        // A     [n][m]
  unsigned short* Y1  = Am  + (size_t)LD * LD;        // A x   [n][bc]
  unsigned short* Y1t = Y1  + (size_t)LD * LD;        // (A x)^T [bc][n]
  unsigned short* Y2  = Y1t + (size_t)LD * LD;        // A^2 x [n][bc]
  unsigned short* wpb = Xc;                           // alias: Xc dead after GEMM1

  transpose_x_kernel<<<dim3(63, 64), 256, 0, stream>>>(x, Xc);
  build_adj_kernel<<<N_NODES, 256, 0, stream>>>(emb, Am);
  gemm_bt_kernel<true ><<<dim3(32, 32), 256, 0, stream>>>(Am, Xc, Y1, Y1t);
  wp_cvt_kernel<<<480, 256, 0, stream>>>(wp, wpb);
  gemm_bt_kernel<false><<<dim3(32, 32), 256, 0, stream>>>(Am, Y1t, Y2, nullptr);
  epilogue_kernel<<<N_NODES, 256, 0, stream>>>(x, emb, wpb, bp, Y1, Y2, out);
}

// Round 4
// 575.072 us; speedup vs baseline: 1.3353x; 1.0364x over previous
//
#include <hip/hip_runtime.h>

typedef __attribute__((ext_vector_type(8))) __bf16 bf16x8;
typedef __attribute__((ext_vector_type(4))) float f32x4;
typedef __attribute__((ext_vector_type(8))) unsigned short u16x8;

#define N_NODES 4000
#define LD 4096
#define KDIM 4000
#define D_EMB 10

__device__ __forceinline__ unsigned short f2bf(float f) {
  union { float f; unsigned int u; } v; v.f = f;
  unsigned int r = v.u + 0x7fffu + ((v.u >> 16) & 1u);
  return (unsigned short)(r >> 16);
}
__device__ __forceinline__ float bf2f(unsigned short s) {
  union { unsigned int u; float f; } v; v.u = ((unsigned int)s) << 16;
  return v.f;
}

#define AS1 __attribute__((address_space(1)))
#define AS3 __attribute__((address_space(3)))
__device__ __forceinline__ void gll16(const void* g, void* l) {
  __builtin_amdgcn_global_load_lds((const AS1 void*)g, (AS3 void*)l, 16, 0, 0);
}

// ---------- x [B,M,C] fp32 -> Xc [bc=b*64+c][m] bf16 (row stride 4096) ----------
__global__ __launch_bounds__(256) void transpose_x_kernel(const float* __restrict__ x,
                                                          unsigned short* __restrict__ Xc) {
  __shared__ float tl[64 * 65];
  const int t = threadIdx.x;
  const int m0 = blockIdx.x * 64;
  const int b = blockIdx.y;
#pragma unroll
  for (int rep = 0; rep < 16; ++rep) {
    int idx = rep * 256 + t;
    int ml = idx >> 6, c = idx & 63;
    int m = m0 + ml;
    tl[ml * 65 + c] = (m < N_NODES) ? x[(b * N_NODES + m) * 64 + c] : 0.f;
  }
  __syncthreads();
  const int c_out = t >> 2, q = t & 3;
  u16x8 v0, v1;
#pragma unroll
  for (int j = 0; j < 8; ++j) v0[j] = f2bf(tl[(q * 16 + j) * 65 + c_out]);
#pragma unroll
  for (int j = 0; j < 8; ++j) v1[j] = f2bf(tl[(q * 16 + 8 + j) * 65 + c_out]);
  unsigned short* dst = Xc + (size_t)(b * 64 + c_out) * LD + m0 + q * 16;
  *(u16x8*)dst = v0;
  *(u16x8*)(dst + 8) = v1;
}

// ---------- A = softmax(relu(emb @ emb^T)) rows, bf16, cols 4000..4095 zeroed ----------
__global__ __launch_bounds__(256) void build_adj_kernel(const float* __restrict__ emb,
                                                        unsigned short* __restrict__ A) {
  __shared__ float e_lds[N_NODES];
  __shared__ float embn[16];
  __shared__ float red[16];
  const int n = blockIdx.x, t = threadIdx.x;
  if (t < D_EMB) embn[t] = emb[n * D_EMB + t];
  __syncthreads();
  float lsum = 0.f;
  for (int m = t; m < N_NODES; m += 256) {
    float dot = 0.f;
#pragma unroll
    for (int d = 0; d < D_EMB; ++d) dot += embn[d] * emb[m * D_EMB + d];
    float e = __expf(fmaxf(dot, 0.f));
    e_lds[m] = e;
    lsum += e;
  }
#pragma unroll
  for (int off = 32; off > 0; off >>= 1) lsum += __shfl_down(lsum, off, 64);
  const int lane = t & 63, wave = t >> 6;
  if (lane == 0) red[wave] = lsum;
  __syncthreads();
  if (t == 0) red[8] = 1.f / (red[0] + red[1] + red[2] + red[3]);
  __syncthreads();
  const float inv = red[8];
  for (int m = t; m < LD; m += 256) {
    float v = (m < N_NODES) ? e_lds[m] * inv : 0.f;
    A[(size_t)n * LD + m] = f2bf(v);
  }
}

// ---------- wp fp32 -> bf16 (into dead Xc region) ----------
__global__ __launch_bounds__(256) void wp_cvt_kernel(const float* __restrict__ wp,
                                                     unsigned short* __restrict__ wpb) {
  int i = blockIdx.x * 256 + threadIdx.x;  // 122880 elems
  if (i < D_EMB * 12288) wpb[i] = f2bf(wp[i]);
}

// ---------- C = A @ B^T, 128x128 tile, BK=32, 16x16x32 MFMA 4x4 frags, 4 blocks/CU ----------
// R1 fragment pattern (measured 3x fewer LDS conflicts than 32x32) + forced 4-wave/EU bound.
template <bool WRITE_T>
__global__ __launch_bounds__(256, 4) void gemm_bt_kernel(const unsigned short* __restrict__ Amat,
                                                         const unsigned short* __restrict__ Bmat,
                                                         unsigned short* __restrict__ Cn,
                                                         unsigned short* __restrict__ Ct) {
  __shared__ __align__(16) char smem[WRITE_T ? (128 * 136 * 2) : (2 * 128 * 32 * 2)];
  unsigned short* At = (unsigned short*)smem;   // [128][32]
  unsigned short* Bt = At + 128 * 32;           // [128][32]
  const int tid = threadIdx.x;
  const int wave = tid >> 6, lane = tid & 63;
  const int bm = blockIdx.y * 128, bn = blockIdx.x * 128;
  const int wm = (wave >> 1) * 64, wn = (wave & 1) * 64;

  const unsigned short* gA = Amat + (size_t)(bm + wave * 32 + (lane >> 2)) * LD + (lane & 3) * 8;
  const unsigned short* gB = Bmat + (size_t)(bn + wave * 32 + (lane >> 2)) * LD + (lane & 3) * 8;
  char* lA0 = smem + wave * 2048;
  char* lA1 = lA0 + 1024;
  char* lB0 = smem + 8192 + wave * 2048;
  char* lB1 = lB0 + 1024;

  f32x4 acc[4][4] = {};
  // frag: A[m=lane&15][k=(lane>>4)*8+j]  start dword banks {0,4,...,28} x 8 lanes = minimal
  const unsigned short* Ap = At + (wm + (lane & 15)) * 32 + (lane >> 4) * 8;
  const unsigned short* Bp = Bt + (wn + (lane & 15)) * 32 + (lane >> 4) * 8;

  for (int kt = 0; kt < KDIM / 32; ++kt) {
    gll16(gA, lA0);
    gll16(gA + 16 * LD, lA1);
    gll16(gB, lB0);
    gll16(gB + 16 * LD, lB1);
    gA += 32; gB += 32;
    __syncthreads();
    bf16x8 af[4], bfr[4];
#pragma unroll
    for (int i = 0; i < 4; ++i) {
      af[i] = *(const bf16x8*)(Ap + i * 512);   // +16 rows per mt
      bfr[i] = *(const bf16x8*)(Bp + i * 512);
    }
#pragma unroll
    for (int mt = 0; mt < 4; ++mt)
#pragma unroll
      for (int nt = 0; nt < 4; ++nt)
        acc[mt][nt] = __builtin_amdgcn_mfma_f32_16x16x32_bf16(af[mt], bfr[nt], acc[mt][nt], 0, 0, 0);
    __syncthreads();
  }

  // C/D layout (16x16): col = lane&15, row = (lane>>4)*4 + reg
#pragma unroll
  for (int mt = 0; mt < 4; ++mt)
#pragma unroll
    for (int nt = 0; nt < 4; ++nt)
#pragma unroll
      for (int r = 0; r < 4; ++r) {
        int row = bm + wm + mt * 16 + (lane >> 4) * 4 + r;
        int col = bn + wn + nt * 16 + (lane & 15);
        Cn[(size_t)row * LD + col] = f2bf(acc[mt][nt][r]);
      }

  if (WRITE_T) {
    unsigned short* tr = (unsigned short*)smem;  // [128 cols][136]
    __syncthreads();
#pragma unroll
    for (int mt = 0; mt < 4; ++mt)
#pragma unroll
      for (int nt = 0; nt < 4; ++nt)
#pragma unroll
        for (int r = 0; r < 4; ++r) {
          int row = wm + mt * 16 + (lane >> 4) * 4 + r;
          int col = wn + nt * 16 + (lane & 15);
          tr[col * 136 + row] = f2bf(acc[mt][nt][r]);
        }
    __syncthreads();
    const int cl = tid >> 1, half = tid & 1;
    const unsigned short* src = tr + cl * 136 + half * 64;
    unsigned short* dst = Ct + (size_t)(bn + cl) * LD + bm + half * 64;
#pragma unroll
    for (int j = 0; j < 8; ++j)
      *(u16x8*)(dst + j * 8) = *(const u16x8*)(src + j * 8);
  }
}

// ---------- fused per-node epilogue via MFMA ----------
#define EST 200  // LDS row stride (elements): 400 B, 16-B aligned
__global__ __launch_bounds__(256) void epilogue_kernel(const float* __restrict__ x,
                                                       const float* __restrict__ emb,
                                                       const unsigned short* __restrict__ wpb,
                                                       const float* __restrict__ bp,
                                                       const unsigned short* __restrict__ Y1,
                                                       const unsigned short* __restrict__ Y2,
                                                       float* __restrict__ out) {
  __shared__ unsigned short Wt[64 * EST];  // [o][ki]
  __shared__ unsigned short xg[64 * EST];  // [b][ki]
  __shared__ float embn[16];
  const int n = blockIdx.x, t = threadIdx.x;
  if (t < D_EMB) embn[t] = emb[n * D_EMB + t];
  __syncthreads();
#pragma unroll 4
  for (int rep = 0; rep < 48; ++rep) {
    int kio = rep * 256 + t;
    int ki = kio >> 6, o = kio & 63;
    float a = 0.f;
#pragma unroll
    for (int d = 0; d < D_EMB; ++d) a += embn[d] * bf2f(wpb[d * 12288 + kio]);
    Wt[o * EST + ki] = f2bf(a);
  }
  for (int idx = t; idx < 4096; idx += 256) {
    int b = idx >> 6, c = idx & 63;
    xg[b * EST + c] = f2bf(x[(size_t)(b * N_NODES + n) * 64 + c]);
  }
  for (int idx = t; idx < 4096; idx += 256) {
    int b = idx >> 6, c = idx & 63;
    xg[b * EST + 64 + c] = Y1[(size_t)n * LD + b * 64 + c];
  }
  for (int idx = t; idx < 4096; idx += 256) {
    int b = idx >> 6, c = idx & 63;
    float v = 2.f * bf2f(Y2[(size_t)n * LD + b * 64 + c]) - bf2f(xg[b * EST + c]);
    xg[b * EST + 128 + c] = f2bf(v);
  }
  __syncthreads();

  const int wave = t >> 6, lane = t & 63, quad = lane >> 4;
  const unsigned short* Apx = xg + (wave * 16 + (lane & 15)) * EST + quad * 8;
  f32x4 acc[4] = {};
#pragma unroll
  for (int step = 0; step < 6; ++step) {
    int koff = step * 32;
    bf16x8 a = *(const bf16x8*)(Apx + koff);
#pragma unroll
    for (int nt = 0; nt < 4; ++nt) {
      bf16x8 bfr = *(const bf16x8*)(Wt + (nt * 16 + (lane & 15)) * EST + quad * 8 + koff);
      acc[nt] = __builtin_amdgcn_mfma_f32_16x16x32_bf16(a, bfr, acc[nt], 0, 0, 0);
    }
  }
  float bias[4];
#pragma unroll
  for (int nt = 0; nt < 4; ++nt) {
    float a = 0.f;
#pragma unroll
    for (int d = 0; d < D_EMB; ++d) a += embn[d] * bp[d * 64 + nt * 16 + (lane & 15)];
    bias[nt] = a;
  }
#pragma unroll
  for (int nt = 0; nt < 4; ++nt)
#pragma unroll
    for (int rr = 0; rr < 4; ++rr) {
      int b_row = wave * 16 + quad * 4 + rr;
      out[(size_t)(b_row * N_NODES + n) * 64 + nt * 16 + (lane & 15)] = acc[nt][rr] + bias[nt];
    }
}

extern "C" void kernel_launch(void* const* d_in, const int* in_sizes, int n_in,
                              void* d_out, int out_size, void* d_ws, size_t ws_size,
                              hipStream_t stream) {
  const float* x   = (const float*)d_in[0];
  const float* emb = (const float*)d_in[1];
  const float* wp  = (const float*)d_in[2];
  const float* bp  = (const float*)d_in[3];
  float* out = (float*)d_out;

  unsigned short* Xc  = (unsigned short*)d_ws;        // x^T [bc][m]; reused for wp_bf16 after GEMM1
  unsigned short* Am  = Xc  + (size_t)LD * LD;        // A     [n][m]
  unsigned short* Y1  = Am  + (size_t)LD * LD;        // A x   [n][bc]
  unsigned short* Y1t = Y1  + (size_t)LD * LD;        // (A x)^T [bc][n]
  unsigned short* Y2  = Y1t + (size_t)LD * LD;        // A^2 x [n][bc]
  unsigned short* wpb = Xc;                           // alias: Xc dead after GEMM1

  transpose_x_kernel<<<dim3(63, 64), 256, 0, stream>>>(x, Xc);
  build_adj_kernel<<<N_NODES, 256, 0, stream>>>(emb, Am);
  gemm_bt_kernel<true ><<<dim3(32, 32), 256, 0, stream>>>(Am, Xc, Y1, Y1t);
  wp_cvt_kernel<<<480, 256, 0, stream>>>(wp, wpb);
  gemm_bt_kernel<false><<<dim3(32, 32), 256, 0, stream>>>(Am, Y1t, Y2, nullptr);
  epilogue_kernel<<<N_NODES, 256, 0, stream>>>(x, emb, wpb, bp, Y1, Y2, out);
}

// Round 5
// 555.474 us; speedup vs baseline: 1.3824x; 1.0353x over previous
//
#include <hip/hip_runtime.h>

typedef __attribute__((ext_vector_type(8))) __bf16 bf16x8;
typedef __attribute__((ext_vector_type(4))) float f32x4;
typedef __attribute__((ext_vector_type(8))) unsigned short u16x8;
typedef __attribute__((ext_vector_type(4))) unsigned short u16x4;

#define N_NODES 4000
#define LD 4096
#define KDIM 4000
#define D_EMB 10

__device__ __forceinline__ unsigned short f2bf(float f) {
  union { float f; unsigned int u; } v; v.f = f;
  unsigned int r = v.u + 0x7fffu + ((v.u >> 16) & 1u);
  return (unsigned short)(r >> 16);
}
__device__ __forceinline__ float bf2f(unsigned short s) {
  union { unsigned int u; float f; } v; v.u = ((unsigned int)s) << 16;
  return v.f;
}

#define AS1 __attribute__((address_space(1)))
#define AS3 __attribute__((address_space(3)))
__device__ __forceinline__ void gll16(const void* g, void* l) {
  __builtin_amdgcn_global_load_lds((const AS1 void*)g, (AS3 void*)l, 16, 0, 0);
}

// ---------- x [B,M,C] fp32 -> Xc [bc=b*64+c][m] bf16 (row stride 4096) ----------
__global__ __launch_bounds__(256) void transpose_x_kernel(const float* __restrict__ x,
                                                          unsigned short* __restrict__ Xc) {
  __shared__ float tl[64 * 65];
  const int t = threadIdx.x;
  const int m0 = blockIdx.x * 64;
  const int b = blockIdx.y;
#pragma unroll
  for (int rep = 0; rep < 16; ++rep) {
    int idx = rep * 256 + t;
    int ml = idx >> 6, c = idx & 63;
    int m = m0 + ml;
    tl[ml * 65 + c] = (m < N_NODES) ? x[(b * N_NODES + m) * 64 + c] : 0.f;
  }
  __syncthreads();
  const int c_out = t >> 2, q = t & 3;
  u16x8 v0, v1;
#pragma unroll
  for (int j = 0; j < 8; ++j) v0[j] = f2bf(tl[(q * 16 + j) * 65 + c_out]);
#pragma unroll
  for (int j = 0; j < 8; ++j) v1[j] = f2bf(tl[(q * 16 + 8 + j) * 65 + c_out]);
  unsigned short* dst = Xc + (size_t)(b * 64 + c_out) * LD + m0 + q * 16;
  *(u16x8*)dst = v0;
  *(u16x8*)(dst + 8) = v1;
}

// ---------- A = softmax(relu(emb @ emb^T)) rows, bf16, cols 4000..4095 zeroed ----------
__global__ __launch_bounds__(256) void build_adj_kernel(const float* __restrict__ emb,
                                                        unsigned short* __restrict__ A) {
  __shared__ float e_lds[N_NODES];
  __shared__ float embn[16];
  __shared__ float red[16];
  const int n = blockIdx.x, t = threadIdx.x;
  if (t < D_EMB) embn[t] = emb[n * D_EMB + t];
  __syncthreads();
  float lsum = 0.f;
  for (int m = t; m < N_NODES; m += 256) {
    float dot = 0.f;
#pragma unroll
    for (int d = 0; d < D_EMB; ++d) dot += embn[d] * emb[m * D_EMB + d];
    float e = __expf(fmaxf(dot, 0.f));
    e_lds[m] = e;
    lsum += e;
  }
#pragma unroll
  for (int off = 32; off > 0; off >>= 1) lsum += __shfl_down(lsum, off, 64);
  const int lane = t & 63, wave = t >> 6;
  if (lane == 0) red[wave] = lsum;
  __syncthreads();
  if (t == 0) red[8] = 1.f / (red[0] + red[1] + red[2] + red[3]);
  __syncthreads();
  const float inv = red[8];
  for (int m = t; m < LD; m += 256) {
    float v = (m < N_NODES) ? e_lds[m] * inv : 0.f;
    A[(size_t)n * LD + m] = f2bf(v);
  }
}

// ---------- wp [10][3][64 i][64 o] fp32 -> wpT [10][o*192 + k*64 + i] bf16 ----------
__global__ __launch_bounds__(256) void wpt_kernel(const float* __restrict__ wp,
                                                  unsigned short* __restrict__ wpT) {
  __shared__ float tl[64 * 65];
  const int dk = blockIdx.x;  // 30 blocks: d*3+k
  const int d = dk / 3, k = dk % 3;
  const float* src = wp + (size_t)dk * 4096;
  const int t = threadIdx.x;
#pragma unroll
  for (int rep = 0; rep < 16; ++rep) {
    int idx = rep * 256 + t;  // i = idx>>6, o = idx&63
    tl[(idx >> 6) * 65 + (idx & 63)] = src[idx];
  }
  __syncthreads();
#pragma unroll
  for (int rep = 0; rep < 16; ++rep) {
    int idx = rep * 256 + t;  // o = idx>>6, i = idx&63
    int o = idx >> 6, i = idx & 63;
    wpT[(size_t)d * 12288 + o * 192 + k * 64 + i] = f2bf(tl[i * 65 + o]);
  }
}

// ---------- W_all[n][j] = sum_d emb[n,d] * wpT[d][j]  (j = o*192+ki), bf16 ----------
__global__ __launch_bounds__(256) void wgen_kernel(const float* __restrict__ emb,
                                                   const unsigned short* __restrict__ wpT,
                                                   unsigned short* __restrict__ W_all) {
  __shared__ float el[50 * D_EMB];
  const int t = threadIdx.x;
  const int j = blockIdx.x * 256 + t;     // 48 j-chunks
  const int n0 = blockIdx.y * 50;         // 80 n-chunks
  for (int idx = t; idx < 50 * D_EMB; idx += 256) el[idx] = emb[n0 * D_EMB + idx];
  __syncthreads();
  float w[D_EMB];
#pragma unroll
  for (int d = 0; d < D_EMB; ++d) w[d] = bf2f(wpT[(size_t)d * 12288 + j]);
  for (int n = 0; n < 50; ++n) {
    float a = 0.f;
#pragma unroll
    for (int d = 0; d < D_EMB; ++d) a += el[n * D_EMB + d] * w[d];
    W_all[(size_t)(n0 + n) * 12288 + j] = f2bf(a);
  }
}

// ---------- C = A @ B^T, 128x128 tile, BK=32, 16x16x32 MFMA 4x4 frags, 4 blocks/CU ----------
template <bool WRITE_T>
__global__ __launch_bounds__(256, 4) void gemm_bt_kernel(const unsigned short* __restrict__ Amat,
                                                         const unsigned short* __restrict__ Bmat,
                                                         unsigned short* __restrict__ Cn,
                                                         unsigned short* __restrict__ Ct) {
  __shared__ __align__(16) char smem[WRITE_T ? (128 * 136 * 2) : (2 * 128 * 32 * 2)];
  unsigned short* At = (unsigned short*)smem;   // [128][32]
  unsigned short* Bt = At + 128 * 32;           // [128][32]
  const int tid = threadIdx.x;
  const int wave = tid >> 6, lane = tid & 63;
  const int bm = blockIdx.y * 128, bn = blockIdx.x * 128;
  const int wm = (wave >> 1) * 64, wn = (wave & 1) * 64;

  const unsigned short* gA = Amat + (size_t)(bm + wave * 32 + (lane >> 2)) * LD + (lane & 3) * 8;
  const unsigned short* gB = Bmat + (size_t)(bn + wave * 32 + (lane >> 2)) * LD + (lane & 3) * 8;
  char* lA0 = smem + wave * 2048;
  char* lA1 = lA0 + 1024;
  char* lB0 = smem + 8192 + wave * 2048;
  char* lB1 = lB0 + 1024;

  f32x4 acc[4][4] = {};
  const unsigned short* Ap = At + (wm + (lane & 15)) * 32 + (lane >> 4) * 8;
  const unsigned short* Bp = Bt + (wn + (lane & 15)) * 32 + (lane >> 4) * 8;

  for (int kt = 0; kt < KDIM / 32; ++kt) {
    gll16(gA, lA0);
    gll16(gA + 16 * LD, lA1);
    gll16(gB, lB0);
    gll16(gB + 16 * LD, lB1);
    gA += 32; gB += 32;
    __syncthreads();
    bf16x8 af[4], bfr[4];
#pragma unroll
    for (int i = 0; i < 4; ++i) {
      af[i] = *(const bf16x8*)(Ap + i * 512);
      bfr[i] = *(const bf16x8*)(Bp + i * 512);
    }
#pragma unroll
    for (int mt = 0; mt < 4; ++mt)
#pragma unroll
      for (int nt = 0; nt < 4; ++nt)
        acc[mt][nt] = __builtin_amdgcn_mfma_f32_16x16x32_bf16(af[mt], bfr[nt], acc[mt][nt], 0, 0, 0);
    __syncthreads();
  }

#pragma unroll
  for (int mt = 0; mt < 4; ++mt)
#pragma unroll
    for (int nt = 0; nt < 4; ++nt)
#pragma unroll
      for (int r = 0; r < 4; ++r) {
        int row = bm + wm + mt * 16 + (lane >> 4) * 4 + r;
        int col = bn + wn + nt * 16 + (lane & 15);
        Cn[(size_t)row * LD + col] = f2bf(acc[mt][nt][r]);
      }

  if (WRITE_T) {
    unsigned short* tr = (unsigned short*)smem;  // [128 cols][136]
    __syncthreads();
#pragma unroll
    for (int mt = 0; mt < 4; ++mt)
#pragma unroll
      for (int nt = 0; nt < 4; ++nt)
#pragma unroll
        for (int r = 0; r < 4; ++r) {
          int row = wm + mt * 16 + (lane >> 4) * 4 + r;
          int col = wn + nt * 16 + (lane & 15);
          tr[col * 136 + row] = f2bf(acc[mt][nt][r]);
        }
    __syncthreads();
    const int cl = tid >> 1, half = tid & 1;
    const unsigned short* src = tr + cl * 136 + half * 64;
    unsigned short* dst = Ct + (size_t)(bn + cl) * LD + bm + half * 64;
#pragma unroll
    for (int j = 0; j < 8; ++j)
      *(u16x8*)(dst + j * 8) = *(const u16x8*)(src + j * 8);
  }
}

// ---------- fused per-node epilogue via MFMA; W streamed from precomputed W_all ----------
#define EST 200  // LDS row stride (elements): 400 B, 16-B aligned
__global__ __launch_bounds__(256) void epilogue_kernel(const float* __restrict__ x,
                                                       const float* __restrict__ emb,
                                                       const unsigned short* __restrict__ W_all,
                                                       const float* __restrict__ bp,
                                                       const unsigned short* __restrict__ Y1,
                                                       const unsigned short* __restrict__ Y2,
                                                       float* __restrict__ out) {
  __shared__ unsigned short Wt[64 * EST];  // [o][ki]
  __shared__ unsigned short xg[64 * EST];  // [b][ki]
  __shared__ float embn[16];
  const int n = blockIdx.x, t = threadIdx.x;
  if (t < D_EMB) embn[t] = emb[n * D_EMB + t];

  // stage W row: 64 o x 192 ki, vectorized u16x8
  {
    const int o = t >> 2, sub = t & 3;
    const unsigned short* srcW = W_all + (size_t)n * 12288 + o * 192 + sub * 48;
    unsigned short* dstW = Wt + o * EST + sub * 48;
#pragma unroll
    for (int c = 0; c < 6; ++c)
      *(u16x8*)(dstW + c * 8) = *(const u16x8*)(srcW + c * 8);
  }
  // xg[b][0..63] = x (float4 loads)
  for (int idx = t; idx < 1024; idx += 256) {
    int b = idx >> 4, c4 = (idx & 15) * 4;
    f32x4 v = *(const f32x4*)(x + (size_t)(b * N_NODES + n) * 64 + c4);
    u16x4 s;
#pragma unroll
    for (int j = 0; j < 4; ++j) s[j] = f2bf(v[j]);
    *(u16x4*)(xg + b * EST + c4) = s;
  }
  // xg[b][64..127] = Y1
  for (int idx = t; idx < 512; idx += 256) {
    int b = idx >> 3, c8 = (idx & 7) * 8;
    *(u16x8*)(xg + b * EST + 64 + c8) = *(const u16x8*)(Y1 + (size_t)n * LD + b * 64 + c8);
  }
  __syncthreads();  // xg x-part complete before cross-thread read below
  // xg[b][128..191] = 2*Y2 - x
  for (int idx = t; idx < 512; idx += 256) {
    int b = idx >> 3, c8 = (idx & 7) * 8;
    u16x8 y2 = *(const u16x8*)(Y2 + (size_t)n * LD + b * 64 + c8);
    u16x8 r;
#pragma unroll
    for (int j = 0; j < 8; ++j)
      r[j] = f2bf(2.f * bf2f(y2[j]) - bf2f(xg[b * EST + c8 + j]));
    *(u16x8*)(xg + b * EST + 128 + c8) = r;
  }
  __syncthreads();

  const int wave = t >> 6, lane = t & 63, quad = lane >> 4;
  const unsigned short* Apx = xg + (wave * 16 + (lane & 15)) * EST + quad * 8;
  f32x4 acc[4] = {};
#pragma unroll
  for (int step = 0; step < 6; ++step) {
    int koff = step * 32;
    bf16x8 a = *(const bf16x8*)(Apx + koff);
#pragma unroll
    for (int nt = 0; nt < 4; ++nt) {
      bf16x8 bfr = *(const bf16x8*)(Wt + (nt * 16 + (lane & 15)) * EST + quad * 8 + koff);
      acc[nt] = __builtin_amdgcn_mfma_f32_16x16x32_bf16(a, bfr, acc[nt], 0, 0, 0);
    }
  }
  float bias[4];
#pragma unroll
  for (int nt = 0; nt < 4; ++nt) {
    float a = 0.f;
#pragma unroll
    for (int d = 0; d < D_EMB; ++d) a += embn[d] * bp[d * 64 + nt * 16 + (lane & 15)];
    bias[nt] = a;
  }
#pragma unroll
  for (int nt = 0; nt < 4; ++nt)
#pragma unroll
    for (int rr = 0; rr < 4; ++rr) {
      int b_row = wave * 16 + quad * 4 + rr;
      out[(size_t)(b_row * N_NODES + n) * 64 + nt * 16 + (lane & 15)] = acc[nt][rr] + bias[nt];
    }
}

extern "C" void kernel_launch(void* const* d_in, const int* in_sizes, int n_in,
                              void* d_out, int out_size, void* d_ws, size_t ws_size,
                              hipStream_t stream) {
  const float* x   = (const float*)d_in[0];
  const float* emb = (const float*)d_in[1];
  const float* wp  = (const float*)d_in[2];
  const float* bp  = (const float*)d_in[3];
  float* out = (float*)d_out;

  // ws: 5 slots of LD*LD bf16 (33.55 MB each, 167.8 MB total — same footprint as R1-R4).
  // Slots 2,3,4 (Xc, Am, Y1t) are dead after GEMM2; wpT + W_all (98.3 MB) overlay them.
  const size_t S = (size_t)LD * LD;
  unsigned short* Y1    = (unsigned short*)d_ws;      // slot 0 (live at epilogue)
  unsigned short* Y2    = Y1 + S;                     // slot 1 (live at epilogue)
  unsigned short* Xc    = Y1 + 2 * S;                 // slot 2
  unsigned short* Am    = Y1 + 3 * S;                 // slot 3
  unsigned short* Y1t   = Y1 + 4 * S;                 // slot 4
  unsigned short* wpT   = Xc;                         // 123 KB, written after GEMM2
  unsigned short* W_all = Xc + 256 * 1024;            // 98.3 MB, spans slots 2-4 tail

  transpose_x_kernel<<<dim3(63, 64), 256, 0, stream>>>(x, Xc);
  build_adj_kernel<<<N_NODES, 256, 0, stream>>>(emb, Am);
  gemm_bt_kernel<true ><<<dim3(32, 32), 256, 0, stream>>>(Am, Xc, Y1, Y1t);
  gemm_bt_kernel<false><<<dim3(32, 32), 256, 0, stream>>>(Am, Y1t, Y2, nullptr);
  wpt_kernel<<<30, 256, 0, stream>>>(wp, wpT);
  wgen_kernel<<<dim3(48, 80), 256, 0, stream>>>(emb, wpT, W_all);
  epilogue_kernel<<<N_NODES, 256, 0, stream>>>(x, emb, W_all, bp, Y1, Y2, out);
}